// Round 4
// baseline (910.902 us; speedup 1.0000x reference)
//
#include <hip/hip_runtime.h>
#include <hip/hip_fp16.h>

#define T_SEQ 256

typedef _Float16 half8 __attribute__((ext_vector_type(8)));
typedef float float4v __attribute__((ext_vector_type(4)));
typedef float float2v __attribute__((ext_vector_type(2)));

__device__ __forceinline__ float fexp2(float x) { return __builtin_amdgcn_exp2f(x); }
__device__ __forceinline__ float frcp(float x) { return __builtin_amdgcn_rcpf(x); }
__device__ __forceinline__ float sigf(float x) { return frcp(1.f + fexp2(-1.4426950408889634f * x)); }
__device__ __forceinline__ float tanhf_(float x) { return 1.f - 2.f * frcp(1.f + fexp2(2.8853900817779268f * x)); }

__device__ __forceinline__ void gload_lds16(const void* g, void* l) {
    __builtin_amdgcn_global_load_lds((const __attribute__((address_space(1))) void*)g,
                                     (__attribute__((address_space(3))) void*)l, 16, 0, 0);
}

// Barrier draining LDS only (global stores/prefetches stay in flight).
__device__ __forceinline__ void relaxed_barrier() {
    __builtin_amdgcn_sched_barrier(0);
    asm volatile("s_waitcnt lgkmcnt(0)" ::: "memory");
    __builtin_amdgcn_s_barrier();
    asm volatile("" ::: "memory");
    __builtin_amdgcn_sched_barrier(0);
}
// l1 variant: also waits own global_load_lds so its LDS writes are visible.
__device__ __forceinline__ void vm_barrier() {
    __builtin_amdgcn_sched_barrier(0);
    asm volatile("s_waitcnt vmcnt(0) lgkmcnt(0)" ::: "memory");
    __builtin_amdgcn_s_barrier();
    asm volatile("" ::: "memory");
    __builtin_amdgcn_sched_barrier(0);
}

// ---------------------------------------------------------------------------
// Layer-0. 128 WGs = 4 chains (n*2+d) x 32 batch-groups of 4 rows. 512 thr.
// Wave w owns gate tiles {w,w+8,w+16,w+24} (i,f,g,o for hc in [16w,16w+16)).
// MFMA A-frag rows: local batches 0-3 valid, rows 4-15 zero (ignored output).
// After MFMA, gates are redistributed via an LDS bounce so each lane owns
// exactly ONE (b,hc) position (c-state = 1 VGPR, 10 TRANS/lane).
// y0f slice (n,t,bg16) = 8KB: [kk(8)=d*4+kk'][l(64)][j(8)] fp16,
//   value = y[row-in-16 = l&15][c = kk'*32 + (l>>4)*8 + j]; this WG owns
//   rows ro0..ro0+3. Writeback: coalesced b128 chunks, one step delayed.
// ---------------------------------------------------------------------------
__global__ __launch_bounds__(512, 1) void lstm_l0(
    const float* __restrict__ x, const float* __restrict__ h0,
    const float* __restrict__ c0, const float* __restrict__ wih0,
    const float* __restrict__ whh0, const float* __restrict__ b0,
    _Float16* __restrict__ y0f) {
    const int wg = blockIdx.x;
    const int chain = wg >> 5, n = chain >> 1, d = chain & 1;
    const int bg4 = wg & 31, bg16 = bg4 >> 2, ro0 = (bg4 & 3) * 4, bbase = bg4 * 4;
    const int tid = threadIdx.x;
    const int wave = tid >> 6, lane = tid & 63, lrow = lane & 15, lgrp = lane >> 4;

    __shared__ __align__(16) float xsT[T_SEQ][4];            // x transposed [t][row]
    __shared__ __align__(16) _Float16 hfrag[2][4][64][8];    // h A-frags, dbuf
    __shared__ __align__(16) float bounce[8][4][4][64];      // gate redistribution

    ((float4v*)hfrag)[tid] = (float4v){0.f, 0.f, 0.f, 0.f};  // zero both buffers
    {   // stage x transposed
        int r = tid >> 7, c2 = (tid & 127) * 2;
        float2v v = *(const float2v*)&x[((bbase + r) * 2 + n) * T_SEQ + c2];
        xsT[c2][r] = v[0];
        xsT[c2 + 1][r] = v[1];
    }
    __syncthreads();
    const int sidx = n * 4 + d;
    if (tid < 64) {  // fill valid rows (local 0-3) of hfrag[0]
        int kk = tid >> 4, q = (tid >> 2) & 3, r = tid & 3;
        const float4v* s4 = (const float4v*)&h0[((size_t)(sidx * 128 + bbase + r)) * 128 + kk * 32 + q * 8];
        float4v v0 = s4[0], v1 = s4[1];
        _Float16* dp = &hfrag[0][kk][16 * q + r][0];
#pragma unroll
        for (int j = 0; j < 4; ++j) { dp[j] = (_Float16)v0[j]; dp[4 + j] = (_Float16)v1[j]; }
    }
    float wi[4], bi[4];
    half8 wf[4][4];
#pragma unroll
    for (int p = 0; p < 4; ++p) {
        int g = (wave + 8 * p) * 16 + lrow;
        wi[p] = wih0[chain * 512 + g];
        bi[p] = b0[chain * 512 + g];
        const float* sg = &whh0[(size_t)(chain * 512 + g) * 128];
#pragma unroll
        for (int kk = 0; kk < 4; ++kk) {
            const float4v* s4 = (const float4v*)&sg[kk * 32 + lgrp * 8];
            float4v v0 = s4[0], v1 = s4[1];
            half8 h;
#pragma unroll
            for (int j = 0; j < 4; ++j) { h[j] = (_Float16)v0[j]; h[4 + j] = (_Float16)v1[j]; }
            wf[p][kk] = h;
        }
    }
    const int hc = wave * 16 + lrow;
    float creg = c0[((size_t)(sidx * 128 + bbase + lgrp)) * 128 + hc];
    __syncthreads();

    const int kkw = hc >> 5, lw = 16 * ((hc >> 3) & 3), jw = hc & 7;
    const int wb = wave * 8 + lane;  // writeback chunk id (valid when lane<8)

    for (int t = 0; t < T_SEQ; ++t) {
        const int cur = t & 1, nxt = cur ^ 1;
        const int tx = d ? (T_SEQ - 1 - t) : t;
        half8 a[4];
#pragma unroll
        for (int kk = 0; kk < 4; ++kk) a[kk] = *(const half8*)&hfrag[cur][kk][lane][0];
        if (t > 0 && lane < 8) {  // delayed coalesced y writeback (h of step t-1)
            const int txp = d ? (T_SEQ - t) : (t - 1);
            const int kkh = wb >> 4, q = (wb >> 2) & 3, ro = wb & 3;
            half8 v = *(const half8*)&hfrag[cur][kkh][16 * q + ro][0];
            *(half8*)&y0f[((size_t)(n * 256 + txp) * 8 + bg16) * 4096 +
                          (size_t)((d * 4 + kkh) * 64 + 16 * q + ro0 + ro) * 8] = v;
        }
        float4v xv = *(const float4v*)&xsT[tx][0];
        float4v accA[4], accB[4];
#pragma unroll
        for (int p = 0; p < 4; ++p) {
#pragma unroll
            for (int jj = 0; jj < 4; ++jj) accA[p][jj] = fmaf(xv[jj], wi[p], bi[p]);
            accB[p] = (float4v){0.f, 0.f, 0.f, 0.f};
        }
#pragma unroll
        for (int p = 0; p < 4; ++p) {  // split accumulators: dep-chain depth 2
            accA[p] = __builtin_amdgcn_mfma_f32_16x16x32_f16(a[0], wf[p][0], accA[p], 0, 0, 0);
            accA[p] = __builtin_amdgcn_mfma_f32_16x16x32_f16(a[1], wf[p][1], accA[p], 0, 0, 0);
            accB[p] = __builtin_amdgcn_mfma_f32_16x16x32_f16(a[2], wf[p][2], accB[p], 0, 0, 0);
            accB[p] = __builtin_amdgcn_mfma_f32_16x16x32_f16(a[3], wf[p][3], accB[p], 0, 0, 0);
        }
#pragma unroll
        for (int p = 0; p < 4; ++p) {  // bounce write: own rows, own region
            float4v g = accA[p] + accB[p];
            *(float4v*)&bounce[wave][p][lgrp][lrow * 4] = g;
        }
        float gate[4];
#pragma unroll
        for (int p = 0; p < 4; ++p) gate[p] = bounce[wave][p][0][lrow * 4 + lgrp];
        float ig = sigf(gate[0]), fg = sigf(gate[1]);
        float gg = tanhf_(gate[2]), og = sigf(gate[3]);
        creg = fmaf(fg, creg, ig * gg);
        float ho = og * tanhf_(creg);
        hfrag[nxt][kkw][lgrp + lw][jw] = (_Float16)ho;  // 1 b16 write/lane
        relaxed_barrier();
    }
    if (lane < 8) {  // final writeback (h of t=255 lives in hfrag[0])
        const int txl = d ? 0 : (T_SEQ - 1);
        const int kkh = wb >> 4, q = (wb >> 2) & 3, ro = wb & 3;
        half8 v = *(const half8*)&hfrag[0][kkh][16 * q + ro][0];
        *(half8*)&y0f[((size_t)(n * 256 + txl) * 8 + bg16) * 4096 +
                      (size_t)((d * 4 + kkh) * 64 + 16 * q + ro0 + ro) * 8] = v;
    }
}

// ---------------------------------------------------------------------------
// Layer-1. 128 WGs (same decomposition); d=1 WGs run only 1 step (t=255 in).
// All weights in VGPRs (wih 64 + wf 32 half8). y bg16-slice (8KB, shared by
// the 4 sibling WGs) prefetched one step ahead via global_load_lds.
// 3 split accumulators (dep-chain depth 4). Same bounce redistribution.
// ---------------------------------------------------------------------------
__global__ __launch_bounds__(512, 1) void lstm_l1(
    const float* __restrict__ h0, const float* __restrict__ c0,
    const float* __restrict__ wih1, const float* __restrict__ whh1,
    const float* __restrict__ b1, const _Float16* __restrict__ y0f,
    float* __restrict__ lo) {
    const int wg = blockIdx.x;
    const int chain = wg >> 5, n = chain >> 1, d = chain & 1;
    const int bg4 = wg & 31, bg16 = bg4 >> 2, ro0 = (bg4 & 3) * 4, bbase = bg4 * 4;
    const int tid = threadIdx.x;
    const int wave = tid >> 6, lane = tid & 63, lrow = lane & 15, lgrp = lane >> 4;

    __shared__ __align__(16) _Float16 ybuf[2][4096];         // y A-frags, dbuf
    __shared__ __align__(16) _Float16 hfrag[2][4][64][8];
    __shared__ __align__(16) float bounce[8][4][4][64];

    ((float4v*)hfrag)[tid] = (float4v){0.f, 0.f, 0.f, 0.f};
    __syncthreads();
    const int sidx = n * 4 + 2 + d;
    if (tid < 64) {  // fill valid rows (ro0..ro0+3 within bg16) of hfrag[0]
        int kk = tid >> 4, q = (tid >> 2) & 3, r = tid & 3;
        const float4v* s4 = (const float4v*)&h0[((size_t)(sidx * 128 + bbase + r)) * 128 + kk * 32 + q * 8];
        float4v v0 = s4[0], v1 = s4[1];
        _Float16* dp = &hfrag[0][kk][16 * q + ro0 + r][0];
#pragma unroll
        for (int j = 0; j < 4; ++j) { dp[j] = (_Float16)v0[j]; dp[4 + j] = (_Float16)v1[j]; }
    }
    float bi[4];
    half8 wih[4][8];
    half8 wf[4][4];
#pragma unroll
    for (int p = 0; p < 4; ++p) {
        int g = (wave + 8 * p) * 16 + lrow;
        bi[p] = b1[chain * 512 + g];
        const float* sg = &wih1[(size_t)(chain * 512 + g) * 256];
#pragma unroll
        for (int kk = 0; kk < 8; ++kk) {
            const float4v* s4 = (const float4v*)&sg[kk * 32 + lgrp * 8];
            float4v v0 = s4[0], v1 = s4[1];
            half8 h;
#pragma unroll
            for (int j = 0; j < 4; ++j) { h[j] = (_Float16)v0[j]; h[4 + j] = (_Float16)v1[j]; }
            wih[p][kk] = h;
        }
        const float* sh = &whh1[(size_t)(chain * 512 + g) * 128];
#pragma unroll
        for (int kk = 0; kk < 4; ++kk) {
            const float4v* s4 = (const float4v*)&sh[kk * 32 + lgrp * 8];
            float4v v0 = s4[0], v1 = s4[1];
            half8 h;
#pragma unroll
            for (int j = 0; j < 4; ++j) { h[j] = (_Float16)v0[j]; h[4 + j] = (_Float16)v1[j]; }
            wf[p][kk] = h;
        }
    }
    const int hc = wave * 16 + lrow;
    float creg = c0[((size_t)(sidx * 128 + bbase + lgrp)) * 128 + hc];

    const int nsteps = d ? 1 : T_SEQ;
    const int t0 = d ? (T_SEQ - 1) : 0;
    gload_lds16(&y0f[((size_t)(n * 256 + t0) * 8 + bg16) * 4096 + (size_t)tid * 8],
                &ybuf[0][wave * 512]);
    asm volatile("s_waitcnt vmcnt(0)" ::: "memory");
    __syncthreads();

    const int kkw = hc >> 5, lw = 16 * ((hc >> 3) & 3), jw = hc & 7;
    const int srcg = bg4 & 3;

    for (int t = 0; t < nsteps; ++t) {
        const int cur = t & 1, nxt = cur ^ 1;
        if (t + 1 < nsteps)  // prefetch next y slice into the other buffer
            gload_lds16(&y0f[((size_t)(n * 256 + (t + 1)) * 8 + bg16) * 4096 + (size_t)tid * 8],
                        &ybuf[nxt][wave * 512]);
        half8 ay[8], ah[4];
#pragma unroll
        for (int kk = 0; kk < 8; ++kk) ay[kk] = *(const half8*)&ybuf[cur][kk * 512 + lane * 8];
#pragma unroll
        for (int kk = 0; kk < 4; ++kk) ah[kk] = *(const half8*)&hfrag[cur][kk][lane][0];
        float4v accA[4], accB[4], accC[4];
#pragma unroll
        for (int p = 0; p < 4; ++p) {
            accA[p] = (float4v){bi[p], bi[p], bi[p], bi[p]};
            accB[p] = (float4v){0.f, 0.f, 0.f, 0.f};
            accC[p] = (float4v){0.f, 0.f, 0.f, 0.f};
        }
#pragma unroll
        for (int p = 0; p < 4; ++p) {  // 3 partials: dep-chain depth 4
            accA[p] = __builtin_amdgcn_mfma_f32_16x16x32_f16(ay[0], wih[p][0], accA[p], 0, 0, 0);
            accA[p] = __builtin_amdgcn_mfma_f32_16x16x32_f16(ay[1], wih[p][1], accA[p], 0, 0, 0);
            accA[p] = __builtin_amdgcn_mfma_f32_16x16x32_f16(ay[2], wih[p][2], accA[p], 0, 0, 0);
            accA[p] = __builtin_amdgcn_mfma_f32_16x16x32_f16(ay[3], wih[p][3], accA[p], 0, 0, 0);
            accB[p] = __builtin_amdgcn_mfma_f32_16x16x32_f16(ay[4], wih[p][4], accB[p], 0, 0, 0);
            accB[p] = __builtin_amdgcn_mfma_f32_16x16x32_f16(ay[5], wih[p][5], accB[p], 0, 0, 0);
            accB[p] = __builtin_amdgcn_mfma_f32_16x16x32_f16(ay[6], wih[p][6], accB[p], 0, 0, 0);
            accB[p] = __builtin_amdgcn_mfma_f32_16x16x32_f16(ay[7], wih[p][7], accB[p], 0, 0, 0);
            accC[p] = __builtin_amdgcn_mfma_f32_16x16x32_f16(ah[0], wf[p][0], accC[p], 0, 0, 0);
            accC[p] = __builtin_amdgcn_mfma_f32_16x16x32_f16(ah[1], wf[p][1], accC[p], 0, 0, 0);
            accC[p] = __builtin_amdgcn_mfma_f32_16x16x32_f16(ah[2], wf[p][2], accC[p], 0, 0, 0);
            accC[p] = __builtin_amdgcn_mfma_f32_16x16x32_f16(ah[3], wf[p][3], accC[p], 0, 0, 0);
        }
#pragma unroll
        for (int p = 0; p < 4; ++p) {
            float4v g = accA[p] + accB[p] + accC[p];
            *(float4v*)&bounce[wave][p][lgrp][lrow * 4] = g;
        }
        float gate[4];
#pragma unroll
        for (int p = 0; p < 4; ++p) gate[p] = bounce[wave][p][srcg][lrow * 4 + lgrp];
        float ig = sigf(gate[0]), fg = sigf(gate[1]);
        float gg = tanhf_(gate[2]), og = sigf(gate[3]);
        creg = fmaf(fg, creg, ig * gg);
        float ho = og * tanhf_(creg);
        hfrag[nxt][kkw][ro0 + lgrp + lw][jw] = (_Float16)ho;
        if (t == nsteps - 1)
            lo[(size_t)(bbase + lgrp) * 512 + n * 256 + d * 128 + hc] = ho;
        vm_barrier();
    }
}

// ---------------------------------------------------------------------------
// FC head: fc0(512->256) -> relu(t+LN(t)) -> fc1(256->256) -> relu(t+LN(t))
// -> fc2(256->64). One WG per batch row, 256 threads.
// ---------------------------------------------------------------------------
__global__ __launch_bounds__(256) void head_k(
    const float* __restrict__ lo,
    const float* __restrict__ w0, const float* __restrict__ bb0,
    const float* __restrict__ a0, const float* __restrict__ g0,
    const float* __restrict__ w1, const float* __restrict__ bb1,
    const float* __restrict__ a1, const float* __restrict__ g1,
    const float* __restrict__ w2, const float* __restrict__ bb2,
    float* __restrict__ out) {
    const int b = blockIdx.x, j = threadIdx.x;
    const int lane = j & 63, wid = j >> 6;
    __shared__ float row[512];
    __shared__ float buf[256];
    __shared__ float redA[4], redB[4];

    row[j] = lo[b * 512 + j];
    row[256 + j] = lo[b * 512 + 256 + j];
    __syncthreads();

    float s = bb0[j];
#pragma unroll 8
    for (int k = 0; k < 512; ++k) s = fmaf(row[k], w0[k * 256 + j], s);
    float v = s, v2 = s * s;
#pragma unroll
    for (int off = 32; off; off >>= 1) { v += __shfl_xor(v, off); v2 += __shfl_xor(v2, off); }
    if (lane == 0) { redA[wid] = v; redB[wid] = v2; }
    __syncthreads();
    float S = redA[0] + redA[1] + redA[2] + redA[3];
    float SS = redB[0] + redB[1] + redB[2] + redB[3];
    float mu = S * (1.f / 256.f);
    float var = (SS - S * mu) * (1.f / 255.f);
    float stdv = sqrtf(var) + 1e-6f;
    float t0 = fmaxf(s + (s - mu) / stdv * a0[j] + g0[j], 0.f);
    buf[j] = t0;
    __syncthreads();

    float s1 = bb1[j];
#pragma unroll 8
    for (int k = 0; k < 256; ++k) s1 = fmaf(buf[k], w1[k * 256 + j], s1);
    v = s1; v2 = s1 * s1;
#pragma unroll
    for (int off = 32; off; off >>= 1) { v += __shfl_xor(v, off); v2 += __shfl_xor(v2, off); }
    if (lane == 0) { redA[wid] = v; redB[wid] = v2; }
    __syncthreads();
    S = redA[0] + redA[1] + redA[2] + redA[3];
    SS = redB[0] + redB[1] + redB[2] + redB[3];
    mu = S * (1.f / 256.f);
    var = (SS - S * mu) * (1.f / 255.f);
    stdv = sqrtf(var) + 1e-6f;
    float t1 = fmaxf(s1 + (s1 - mu) / stdv * a1[j] + g1[j], 0.f);
    __syncthreads();
    buf[j] = t1;
    __syncthreads();

    if (j < 64) {
        float s2 = bb2[j];
#pragma unroll 8
        for (int k = 0; k < 256; ++k) s2 = fmaf(buf[k], w2[k * 64 + j], s2);
        out[b * 64 + j] = s2;
    }
}

extern "C" void kernel_launch(void* const* d_in, const int* in_sizes, int n_in,
                              void* d_out, int out_size, void* d_ws, size_t ws_size,
                              hipStream_t stream) {
    const float* x    = (const float*)d_in[0];
    const float* h0   = (const float*)d_in[1];
    const float* c0   = (const float*)d_in[2];
    const float* wih0 = (const float*)d_in[3];
    const float* whh0 = (const float*)d_in[4];
    const float* bb0  = (const float*)d_in[5];
    const float* wih1 = (const float*)d_in[6];
    const float* whh1 = (const float*)d_in[7];
    const float* bb1  = (const float*)d_in[8];
    const float* wfc0 = (const float*)d_in[9];
    const float* bfc0 = (const float*)d_in[10];
    const float* ln0a = (const float*)d_in[11];
    const float* ln0b = (const float*)d_in[12];
    const float* wfc1 = (const float*)d_in[13];
    const float* bfc1 = (const float*)d_in[14];
    const float* ln1a = (const float*)d_in[15];
    const float* ln1b = (const float*)d_in[16];
    const float* wfc2 = (const float*)d_in[17];
    const float* bfc2 = (const float*)d_in[18];

    // workspace: y0f fp16 [2][256][8][4096] = 32 MiB; lo fp32 [128][512]
    char* ws = (char*)d_ws;
    _Float16* y0f = (_Float16*)ws;
    float*    lo  = (float*)(ws + (size_t)33554432);

    lstm_l0<<<dim3(128), dim3(512), 0, stream>>>(x, h0, c0, wih0, whh0, bb0, y0f);
    lstm_l1<<<dim3(128), dim3(512), 0, stream>>>(h0, c0, wih1, whh1, bb1, y0f, lo);
    head_k<<<dim3(128), dim3(256), 0, stream>>>(lo, wfc0, bfc0, ln0a, ln0b,
                                                wfc1, bfc1, ln1a, ln1b, wfc2, bfc2,
                                                (float*)d_out);
}

// Round 5
// 818.931 us; speedup vs baseline: 1.1123x; 1.1123x over previous
//
#include <hip/hip_runtime.h>
#include <hip/hip_fp16.h>

#define T_SEQ 256

typedef _Float16 half8 __attribute__((ext_vector_type(8)));
typedef float float4v __attribute__((ext_vector_type(4)));
typedef unsigned long long u64;

__device__ __forceinline__ float fexp2(float x) { return __builtin_amdgcn_exp2f(x); }
__device__ __forceinline__ float frcp(float x) { return __builtin_amdgcn_rcpf(x); }

// Fused LSTM gating: 5 exp2 + 3 rcp (vs 10 TRANS naive). Clamps keep every
// exp2 arg <= ~43 so products stay finite (no inf*0 NaN path).
__device__ __forceinline__ float lstm_gate(float gi, float gf, float gg, float go, float& c) {
    const float K1 = -1.4426950408889634f;  // -log2(e)
    const float K2 = 2.8853900817779268f;   // 2*log2(e)
    gi = __builtin_amdgcn_fmed3f(gi, -30.f, 30.f);
    gf = __builtin_amdgcn_fmed3f(gf, -30.f, 30.f);
    gg = __builtin_amdgcn_fmed3f(gg, -30.f, 30.f);
    go = __builtin_amdgcn_fmed3f(go, -30.f, 30.f);
    float F2 = fexp2(K1 * gf);                    // sig(f) = 1/(1+F2)
    float A2 = fexp2(K1 * gi);                    // sig(i) = 1/(1+A2)
    float G2 = fexp2(K2 * gg);                    // tanh(g) = (G2-1)/(G2+1)
    float O2 = fexp2(K1 * go);
    float rf  = frcp(1.f + F2);
    float rag = frcp((1.f + A2) * (1.f + G2));
    c = c * rf + (G2 - 1.f) * rag;                // sig(f)*c + sig(i)*tanh(g)
    float cc = __builtin_amdgcn_fmed3f(c, -20.f, 20.f);
    float C2 = fexp2(K2 * cc);
    float roc = frcp((1.f + O2) * (1.f + C2));
    return (C2 - 1.f) * roc;                      // sig(o)*tanh(c)
}

__device__ __forceinline__ void gload_lds16(const void* g, void* l) {
    __builtin_amdgcn_global_load_lds((const __attribute__((address_space(1))) void*)g,
                                     (__attribute__((address_space(3))) void*)l, 16, 0, 0);
}

// Barrier draining LDS only (global stores stay in flight).
__device__ __forceinline__ void relaxed_barrier() {
    __builtin_amdgcn_sched_barrier(0);
    asm volatile("s_waitcnt lgkmcnt(0)" ::: "memory");
    __builtin_amdgcn_s_barrier();
    asm volatile("" ::: "memory");
    __builtin_amdgcn_sched_barrier(0);
}
// l1 variant: also drains own global_load_lds (issued earlier this step).
__device__ __forceinline__ void vm_barrier() {
    __builtin_amdgcn_sched_barrier(0);
    asm volatile("s_waitcnt vmcnt(0) lgkmcnt(0)" ::: "memory");
    __builtin_amdgcn_s_barrier();
    asm volatile("" ::: "memory");
    __builtin_amdgcn_sched_barrier(0);
}

// ---------------------------------------------------------------------------
// Layer-0. 32 WGs = 4 chains (n*2+d) x 8 batch-groups of 16 rows. 512 thr.
// Wave w owns gate tiles {w,w+8,w+16,w+24} (i,f,g,o for hc in [16w,16w+16)).
// y0f slice (n,t,bg) = 8KB: [kk(8)=d*4+kk'][l(64)][j(8)] fp16,
//   frag: y[row=l&15][c = kk'*32 + (l>>4)*8 + j].
// Writeback: all 512 threads store b64 from the completed hfrag, 1-step delay.
// ---------------------------------------------------------------------------
__global__ __launch_bounds__(512, 1) void lstm_l0(
    const float* __restrict__ x, const float* __restrict__ h0,
    const float* __restrict__ c0, const float* __restrict__ wih0,
    const float* __restrict__ whh0, const float* __restrict__ b0,
    _Float16* __restrict__ y0f) {
    const int wg = blockIdx.x;
    const int chain = wg >> 3, n = chain >> 1, d = chain & 1;
    const int bg = wg & 7, bbase = bg * 16;
    const int tid = threadIdx.x;
    const int wave = tid >> 6, lane = tid & 63, lrow = lane & 15, lgrp = lane >> 4;

    __shared__ __align__(16) float xsT[T_SEQ][16];
    __shared__ __align__(16) _Float16 hfrag[2][4][64][8];

    {   // stage x transposed (once)
        int r = tid >> 5, ck = tid & 31;
        const float* xr = &x[((bbase + r) * 2 + n) * T_SEQ + ck * 8];
        float4v v0 = *(const float4v*)xr, v1 = *(const float4v*)(xr + 4);
#pragma unroll
        for (int i = 0; i < 4; ++i) { xsT[ck * 8 + i][r] = v0[i]; xsT[ck * 8 + 4 + i][r] = v1[i]; }
    }
    const int sidx = n * 4 + d;
    for (int idx = tid; idx < 256; idx += 512) {
        int kk = idx >> 6, l = idx & 63;
        int b = bbase + (l & 15), k0 = kk * 32 + (l >> 4) * 8;
        const float4v* s4 = (const float4v*)&h0[((size_t)(sidx * 128 + b)) * 128 + k0];
        float4v v0 = s4[0], v1 = s4[1];
        _Float16* dp = &hfrag[0][kk][l][0];
#pragma unroll
        for (int j = 0; j < 4; ++j) { dp[j] = (_Float16)v0[j]; dp[4 + j] = (_Float16)v1[j]; }
    }
    float wi[4], bi[4];
    half8 wf[4][4];
#pragma unroll
    for (int p = 0; p < 4; ++p) {
        int g = (wave + 8 * p) * 16 + lrow;
        wi[p] = wih0[chain * 512 + g];
        bi[p] = b0[chain * 512 + g];
        const float* sg = &whh0[(size_t)(chain * 512 + g) * 128];
#pragma unroll
        for (int kk = 0; kk < 4; ++kk) {
            const float4v* s4 = (const float4v*)&sg[kk * 32 + lgrp * 8];
            float4v v0 = s4[0], v1 = s4[1];
            half8 h;
#pragma unroll
            for (int j = 0; j < 4; ++j) { h[j] = (_Float16)v0[j]; h[4 + j] = (_Float16)v1[j]; }
            wf[p][kk] = h;
        }
    }
    const int hc = wave * 16 + lrow;
    float creg[4];
#pragma unroll
    for (int jj = 0; jj < 4; ++jj)
        creg[jj] = c0[((size_t)(sidx * 128 + bbase + 4 * lgrp + jj)) * 128 + hc];
    __syncthreads();

    const int kkw = hc >> 5, lw = 16 * ((hc >> 3) & 3), jw = hc & 7;

    for (int t = 0; t < T_SEQ; ++t) {
        const int cur = t & 1, nxt = cur ^ 1;
        const int tx = d ? (T_SEQ - 1 - t) : t;
        half8 a[4];
#pragma unroll
        for (int kk = 0; kk < 4; ++kk) a[kk] = *(const half8*)&hfrag[cur][kk][lane][0];
        if (t > 0) {  // delayed y writeback: h(t-1), all 512 threads, b64 each
            const int txp = d ? (T_SEQ - t) : (t - 1);
            u64 v = ((const u64*)&hfrag[cur][0][0][0])[tid];
            ((u64*)&y0f[((size_t)(n * 256 + txp) * 8 + bg) * 4096 + d * 2048])[tid] = v;
        }
        float4v xv = *(const float4v*)&xsT[tx][4 * lgrp];
        float4v accA[4], accB[4];
#pragma unroll
        for (int p = 0; p < 4; ++p) {
#pragma unroll
            for (int jj = 0; jj < 4; ++jj) accA[p][jj] = fmaf(xv[jj], wi[p], bi[p]);
            accB[p] = (float4v){0.f, 0.f, 0.f, 0.f};
        }
#pragma unroll
        for (int p = 0; p < 4; ++p) {  // split acc: dep depth 2
            accA[p] = __builtin_amdgcn_mfma_f32_16x16x32_f16(a[0], wf[p][0], accA[p], 0, 0, 0);
            accA[p] = __builtin_amdgcn_mfma_f32_16x16x32_f16(a[1], wf[p][1], accA[p], 0, 0, 0);
            accB[p] = __builtin_amdgcn_mfma_f32_16x16x32_f16(a[2], wf[p][2], accB[p], 0, 0, 0);
            accB[p] = __builtin_amdgcn_mfma_f32_16x16x32_f16(a[3], wf[p][3], accB[p], 0, 0, 0);
        }
#pragma unroll
        for (int jj = 0; jj < 4; ++jj) {
            float gi = accA[0][jj] + accB[0][jj];
            float gf = accA[1][jj] + accB[1][jj];
            float gg = accA[2][jj] + accB[2][jj];
            float go = accA[3][jj] + accB[3][jj];
            float ho = lstm_gate(gi, gf, gg, go, creg[jj]);
            hfrag[nxt][kkw][lw + 4 * lgrp + jj][jw] = (_Float16)ho;
        }
        relaxed_barrier();
    }
    {   // final writeback: h(255) lives in hfrag[0]
        const int txl = d ? 0 : (T_SEQ - 1);
        u64 v = ((const u64*)&hfrag[0][0][0][0])[tid];
        ((u64*)&y0f[((size_t)(n * 256 + txl) * 8 + bg) * 4096 + d * 2048])[tid] = v;
    }
}

// ---------------------------------------------------------------------------
// Layer-1. 32 WGs, same decomposition; d=1 WGs run 1 step (t=255 input).
// Weights resident (wih 128 + wf 64 regs). ybuf = 3-slot ring filled by
// global_load_lds two steps ahead. Key: the y-projection accY(t+1) is
// computed DURING step t (independent of h(t+1)) so its MFMAs + LDS reads
// hide under step t's gating TRANS chain. H-MFMAs consume accY as C-in.
// Branchless body => one scheduling region.
// ---------------------------------------------------------------------------
__global__ __launch_bounds__(512, 1) void lstm_l1(
    const float* __restrict__ h0, const float* __restrict__ c0,
    const float* __restrict__ wih1, const float* __restrict__ whh1,
    const float* __restrict__ b1, const _Float16* __restrict__ y0f,
    float* __restrict__ lo) {
    const int wg = blockIdx.x;
    const int chain = wg >> 3, n = chain >> 1, d = chain & 1;
    const int bg = wg & 7, bbase = bg * 16;
    const int tid = threadIdx.x;
    const int wave = tid >> 6, lane = tid & 63, lrow = lane & 15, lgrp = lane >> 4;

    __shared__ __align__(16) _Float16 ybuf[3][4096];   // y A-frag ring (24KB)
    __shared__ __align__(16) _Float16 hfrag[2][4][64][8];

    const int sidx = n * 4 + 2 + d;
    for (int idx = tid; idx < 256; idx += 512) {
        int kk = idx >> 6, l = idx & 63;
        int b = bbase + (l & 15), k0 = kk * 32 + (l >> 4) * 8;
        const float4v* s4 = (const float4v*)&h0[((size_t)(sidx * 128 + b)) * 128 + k0];
        float4v v0 = s4[0], v1 = s4[1];
        _Float16* dp = &hfrag[0][kk][l][0];
#pragma unroll
        for (int j = 0; j < 4; ++j) { dp[j] = (_Float16)v0[j]; dp[4 + j] = (_Float16)v1[j]; }
    }
    float bi[4];
    half8 wih[4][8];   // 128 regs
    half8 wf[4][4];    // 64 regs
#pragma unroll
    for (int p = 0; p < 4; ++p) {
        int g = (wave + 8 * p) * 16 + lrow;
        bi[p] = b1[chain * 512 + g];
        const float* sg = &wih1[(size_t)(chain * 512 + g) * 256];
#pragma unroll
        for (int kk = 0; kk < 8; ++kk) {
            const float4v* s4 = (const float4v*)&sg[kk * 32 + lgrp * 8];
            float4v v0 = s4[0], v1 = s4[1];
            half8 h;
#pragma unroll
            for (int j = 0; j < 4; ++j) { h[j] = (_Float16)v0[j]; h[4 + j] = (_Float16)v1[j]; }
            wih[p][kk] = h;
        }
        const float* sh = &whh1[(size_t)(chain * 512 + g) * 128];
#pragma unroll
        for (int kk = 0; kk < 4; ++kk) {
            const float4v* s4 = (const float4v*)&sh[kk * 32 + lgrp * 8];
            float4v v0 = s4[0], v1 = s4[1];
            half8 h;
#pragma unroll
            for (int j = 0; j < 4; ++j) { h[j] = (_Float16)v0[j]; h[4 + j] = (_Float16)v1[j]; }
            wf[p][kk] = h;
        }
    }
    const int hc = wave * 16 + lrow;
    float creg[4];
#pragma unroll
    for (int jj = 0; jj < 4; ++jj)
        creg[jj] = c0[((size_t)(sidx * 128 + bbase + 4 * lgrp + jj)) * 128 + hc];

    const int nsteps = d ? 1 : T_SEQ;
    const int t0 = d ? (T_SEQ - 1) : 0;
    // prologue: fill ring slots 0 (y(t0)) and 1 (y(t0+1) if it exists)
    gload_lds16(&y0f[((size_t)(n * 256 + t0) * 8 + bg) * 4096 + (size_t)tid * 8],
                &ybuf[0][wave * 512]);
    if (nsteps > 1)
        gload_lds16(&y0f[((size_t)(n * 256 + t0 + 1) * 8 + bg) * 4096 + (size_t)tid * 8],
                    &ybuf[1][wave * 512]);
    asm volatile("s_waitcnt vmcnt(0)" ::: "memory");
    __syncthreads();

    // accY for step 0
    float4v accY[4];
#pragma unroll
    for (int p = 0; p < 4; ++p) accY[p] = (float4v){bi[p], bi[p], bi[p], bi[p]};
#pragma unroll
    for (int kk = 0; kk < 8; ++kk) {
        half8 ay = *(const half8*)&ybuf[0][kk * 512 + lane * 8];
#pragma unroll
        for (int p = 0; p < 4; ++p)
            accY[p] = __builtin_amdgcn_mfma_f32_16x16x32_f16(ay, wih[p][kk], accY[p], 0, 0, 0);
    }

    const int kkw = hc >> 5, lw = 16 * ((hc >> 3) & 3), jw = hc & 7;
    // ring slot trackers: sRd = slot holding y(t+1); sFl = slot to fill y(t+2)
    int sRd = 1, sFl = 2, sOld = 0;

    for (int t = 0; t < nsteps; ++t) {
        const int cur = t & 1, nxt = cur ^ 1;
        // fill slot sFl with y(t+2) (clamped index; harmless duplicate at tail)
        const int tf = (t + 2 < nsteps) ? (t + 2) : (nsteps - 1);
        gload_lds16(&y0f[((size_t)(n * 256 + t0 + tf) * 8 + bg) * 4096 + (size_t)tid * 8],
                    &ybuf[sFl][wave * 512]);
        // ---- H part (critical path); C-in = accY => zero-copy
        float4v acc[4];
        {
            half8 a0 = *(const half8*)&hfrag[cur][0][lane][0];
            half8 a1 = *(const half8*)&hfrag[cur][1][lane][0];
#pragma unroll
            for (int p = 0; p < 4; ++p)
                acc[p] = __builtin_amdgcn_mfma_f32_16x16x32_f16(a0, wf[p][0], accY[p], 0, 0, 0);
#pragma unroll
            for (int p = 0; p < 4; ++p)
                acc[p] = __builtin_amdgcn_mfma_f32_16x16x32_f16(a1, wf[p][1], acc[p], 0, 0, 0);
            half8 a2 = *(const half8*)&hfrag[cur][2][lane][0];
            half8 a3 = *(const half8*)&hfrag[cur][3][lane][0];
#pragma unroll
            for (int p = 0; p < 4; ++p)
                acc[p] = __builtin_amdgcn_mfma_f32_16x16x32_f16(a2, wf[p][2], acc[p], 0, 0, 0);
#pragma unroll
            for (int p = 0; p < 4; ++p)
                acc[p] = __builtin_amdgcn_mfma_f32_16x16x32_f16(a3, wf[p][3], acc[p], 0, 0, 0);
        }
        // ---- Y projection for step t+1 (independent; hides under gating).
        // Always executed (branchless). On the last step it consumes stale
        // LDS data and its result is never used.
        const _Float16* yb = &ybuf[sRd][lane * 8];
#pragma unroll
        for (int p = 0; p < 4; ++p) accY[p] = (float4v){bi[p], bi[p], bi[p], bi[p]};
#pragma unroll
        for (int kk = 0; kk < 8; ++kk) {
            half8 ay = *(const half8*)&yb[kk * 512];
#pragma unroll
            for (int p = 0; p < 4; ++p)
                accY[p] = __builtin_amdgcn_mfma_f32_16x16x32_f16(ay, wih[p][kk], accY[p], 0, 0, 0);
        }
        // ---- gating (TRANS chain; scheduler interleaves Y-MFMAs under it)
        float hout[4];
#pragma unroll
        for (int jj = 0; jj < 4; ++jj)
            hout[jj] = lstm_gate(acc[0][jj], acc[1][jj], acc[2][jj], acc[3][jj], creg[jj]);
#pragma unroll
        for (int jj = 0; jj < 4; ++jj)
            hfrag[nxt][kkw][lw + 4 * lgrp + jj][jw] = (_Float16)hout[jj];
        if (t == nsteps - 1) {
#pragma unroll
            for (int jj = 0; jj < 4; ++jj)
                lo[(size_t)(bbase + 4 * lgrp + jj) * 512 + n * 256 + d * 128 + hc] = hout[jj];
        }
        // rotate ring
        int tmp = sOld; sOld = sRd; sRd = sFl; sFl = tmp;
        vm_barrier();  // drains this step's gload + LDS writes
    }
}

// ---------------------------------------------------------------------------
// FC head: fc0(512->256) -> relu(t+LN(t)) -> fc1(256->256) -> relu(t+LN(t))
// -> fc2(256->64). One WG per batch row, 256 threads.
// ---------------------------------------------------------------------------
__global__ __launch_bounds__(256) void head_k(
    const float* __restrict__ lo,
    const float* __restrict__ w0, const float* __restrict__ bb0,
    const float* __restrict__ a0, const float* __restrict__ g0,
    const float* __restrict__ w1, const float* __restrict__ bb1,
    const float* __restrict__ a1, const float* __restrict__ g1,
    const float* __restrict__ w2, const float* __restrict__ bb2,
    float* __restrict__ out) {
    const int b = blockIdx.x, j = threadIdx.x;
    const int lane = j & 63, wid = j >> 6;
    __shared__ float row[512];
    __shared__ float buf[256];
    __shared__ float redA[4], redB[4];

    row[j] = lo[b * 512 + j];
    row[256 + j] = lo[b * 512 + 256 + j];
    __syncthreads();

    float s = bb0[j];
#pragma unroll 8
    for (int k = 0; k < 512; ++k) s = fmaf(row[k], w0[k * 256 + j], s);
    float v = s, v2 = s * s;
#pragma unroll
    for (int off = 32; off; off >>= 1) { v += __shfl_xor(v, off); v2 += __shfl_xor(v2, off); }
    if (lane == 0) { redA[wid] = v; redB[wid] = v2; }
    __syncthreads();
    float S = redA[0] + redA[1] + redA[2] + redA[3];
    float SS = redB[0] + redB[1] + redB[2] + redB[3];
    float mu = S * (1.f / 256.f);
    float var = (SS - S * mu) * (1.f / 255.f);
    float stdv = sqrtf(var) + 1e-6f;
    float t0 = fmaxf(s + (s - mu) / stdv * a0[j] + g0[j], 0.f);
    buf[j] = t0;
    __syncthreads();

    float s1 = bb1[j];
#pragma unroll 8
    for (int k = 0; k < 256; ++k) s1 = fmaf(buf[k], w1[k * 256 + j], s1);
    v = s1; v2 = s1 * s1;
#pragma unroll
    for (int off = 32; off; off >>= 1) { v += __shfl_xor(v, off); v2 += __shfl_xor(v2, off); }
    if (lane == 0) { redA[wid] = v; redB[wid] = v2; }
    __syncthreads();
    S = redA[0] + redA[1] + redA[2] + redA[3];
    SS = redB[0] + redB[1] + redB[2] + redB[3];
    mu = S * (1.f / 256.f);
    var = (SS - S * mu) * (1.f / 255.f);
    stdv = sqrtf(var) + 1e-6f;
    float t1 = fmaxf(s1 + (s1 - mu) / stdv * a1[j] + g1[j], 0.f);
    __syncthreads();
    buf[j] = t1;
    __syncthreads();

    if (j < 64) {
        float s2 = bb2[j];
#pragma unroll 8
        for (int k = 0; k < 256; ++k) s2 = fmaf(buf[k], w2[k * 64 + j], s2);
        out[b * 64 + j] = s2;
    }
}

extern "C" void kernel_launch(void* const* d_in, const int* in_sizes, int n_in,
                              void* d_out, int out_size, void* d_ws, size_t ws_size,
                              hipStream_t stream) {
    const float* x    = (const float*)d_in[0];
    const float* h0   = (const float*)d_in[1];
    const float* c0   = (const float*)d_in[2];
    const float* wih0 = (const float*)d_in[3];
    const float* whh0 = (const float*)d_in[4];
    const float* bb0  = (const float*)d_in[5];
    const float* wih1 = (const float*)d_in[6];
    const float* whh1 = (const float*)d_in[7];
    const float* bb1  = (const float*)d_in[8];
    const float* wfc0 = (const float*)d_in[9];
    const float* bfc0 = (const float*)d_in[10];
    const float* ln0a = (const float*)d_in[11];
    const float* ln0b = (const float*)d_in[12];
    const float* wfc1 = (const float*)d_in[13];
    const float* bfc1 = (const float*)d_in[14];
    const float* ln1a = (const float*)d_in[15];
    const float* ln1b = (const float*)d_in[16];
    const float* wfc2 = (const float*)d_in[17];
    const float* bfc2 = (const float*)d_in[18];

    // workspace: y0f fp16 [2][256][8][4096] = 32 MiB; lo fp32 [128][512]
    char* ws = (char*)d_ws;
    _Float16* y0f = (_Float16*)ws;
    float*    lo  = (float*)(ws + (size_t)33554432);

    lstm_l0<<<dim3(32), dim3(512), 0, stream>>>(x, h0, c0, wih0, whh0, bb0, y0f);
    lstm_l1<<<dim3(32), dim3(512), 0, stream>>>(h0, c0, wih1, whh1, bb1, y0f, lo);
    head_k<<<dim3(128), dim3(256), 0, stream>>>(lo, wfc0, bfc0, ln0a, ln0b,
                                                wfc1, bfc1, ln1a, ln1b, wfc2, bfc2,
                                                (float*)d_out);
}